// Round 1
// baseline (303.804 us; speedup 1.0000x reference)
//
#include <hip/hip_runtime.h>

#define HW 50176          // 224*224
#define NBLK 3136         // 4*HW / 64 pixels per block

typedef unsigned short u16x8 __attribute__((ext_vector_type(8)));
typedef __bf16 bf16x8 __attribute__((ext_vector_type(8)));
typedef float f32x4 __attribute__((ext_vector_type(4)));

// LDS map (80 KB total -> 2 WGs/CU)
#define L_WBUF 0              // 32 KB weight staging buffer
#define L_XMID 32768          // 16 KB  x=att*value [64][128] bf16 S=256
#define L_XD2  32768          //  8 KB  d2 input    [64][32]  bf16 S=128 (reuse)
#define L_XD3  40960          //  8 KB  d3 input    [64][32]  bf16 S=128 (reuse)
#define L_XCAT 49152          // 32 KB  concat      [64][160] bf16 S=512
#define L_XQ1  49152          //  8 KB  q1 out      [64][64]  bf16 S=128 (reuse, dead before XCAT)
#define LDS_BYTES 81920

static __device__ __forceinline__ unsigned short f2bf(float x) {
    unsigned u = __builtin_bit_cast(unsigned, x);
    unsigned r = u + 0x7fffu + ((u >> 16) & 1u);   // RNE
    return (unsigned short)(r >> 16);
}

static __device__ __forceinline__ float red16_sum(float v) {
    v += __shfl_xor(v, 1); v += __shfl_xor(v, 2);
    v += __shfl_xor(v, 4); v += __shfl_xor(v, 8);
    return v;
}
static __device__ __forceinline__ float red16_max(float v) {
    v = fmaxf(v, __shfl_xor(v, 1)); v = fmaxf(v, __shfl_xor(v, 2));
    v = fmaxf(v, __shfl_xor(v, 4)); v = fmaxf(v, __shfl_xor(v, 8));
    return v;
}

#define MFMA16(acc, a, bfr) (acc) = __builtin_amdgcn_mfma_f32_16x16x32_bf16( \
        __builtin_bit_cast(bf16x8, (a)), __builtin_bit_cast(bf16x8, (bfr)), (acc), 0, 0, 0)

// stage W[NS][K] (f32, row-major) -> LDS bf16 rows, row stride S bytes, XOR swizzle mask
static __device__ __forceinline__ void stageW(char* dst, const float* __restrict__ W,
                                              int NS, int K, int S, int mask, int tid) {
    const int kh = K >> 1;
    const int pairs = NS * kh;
    for (int q = tid; q < pairs; q += 256) {
        int n = q / kh;
        int kp = q - n * kh;
        float a = W[n * K + 2 * kp];
        float c = W[n * K + 2 * kp + 1];
        unsigned val = (unsigned)f2bf(a) | ((unsigned)f2bf(c) << 16);
        *(unsigned*)(dst + n * S + ((4 * kp) ^ ((n & mask) << 4))) = val;
    }
}

static __device__ __forceinline__ u16x8 ldB(const char* lds, int S, int mask,
                                            int t, int kc, int lane) {
    int n = t * 16 + (lane & 15);
    int kb = kc * 64 + ((lane >> 4) << 4);
    return *(const u16x8*)(lds + n * S + (kb ^ ((n & mask) << 4)));
}
static __device__ __forceinline__ u16x8 ldA(const char* lds, int S, int mask,
                                            int rA, int kc, int lane) {
    int kb = kc * 64 + ((lane >> 4) << 4);
    return *(const u16x8*)(lds + rA * S + (kb ^ ((rA & mask) << 4)));
}
static __device__ __forceinline__ void stD(char* lds, int S, int mask,
                                           int rD, int c, float v) {
    *(unsigned short*)(lds + rD * S + ((2 * c) ^ ((rD & mask) << 4))) = f2bf(v);
}

__global__ __launch_bounds__(256, 2) void fused_attres(
        const float* __restrict__ kvin, const float* __restrict__ qin,
        const float* __restrict__ Wk,  const float* __restrict__ bk,
        const float* __restrict__ Wv,  const float* __restrict__ bv,
        const float* __restrict__ Wq1, const float* __restrict__ bq1,
        const float* __restrict__ Wq2, const float* __restrict__ bq2,
        const float* __restrict__ Wat, const float* __restrict__ bat,
        const float* __restrict__ gat, const float* __restrict__ beat,
        const float* __restrict__ Wre, const float* __restrict__ gre, const float* __restrict__ bere,
        const float* __restrict__ Wd1, const float* __restrict__ gd1, const float* __restrict__ bed1,
        const float* __restrict__ Wd2, const float* __restrict__ gd2, const float* __restrict__ bed2,
        const float* __restrict__ Wd3, const float* __restrict__ bd3,
        float* __restrict__ out)
{
    __shared__ __align__(16) char lds[LDS_BYTES];
    const int tid  = threadIdx.x;
    const int lane = tid & 63;
    const int wid  = tid >> 6;
    const int l15  = lane & 15;
    const int lg   = lane >> 4;
    const int P0 = blockIdx.x * 64;
    const int b  = P0 / HW;
    const int p0 = P0 - b * HW;
    const int rA = wid * 16 + l15;      // this lane's A-fragment pixel-row in the 64-tile
    char* wb = lds + L_WBUF;

    // ---------- A fragments of raw inputs straight from global (f32 -> bf16) ----------
    u16x8 aq[4], akv[8];
    {
        const float* qp = qin + (size_t)b * 128 * HW + (p0 + rA);
        #pragma unroll
        for (int kc = 0; kc < 4; ++kc)
            #pragma unroll
            for (int j = 0; j < 8; ++j)
                aq[kc][j] = f2bf(qp[(size_t)(kc * 32 + lg * 8 + j) * HW]);
        const float* kp = kvin + (size_t)b * 256 * HW + (p0 + rA);
        #pragma unroll
        for (int kc = 0; kc < 8; ++kc)
            #pragma unroll
            for (int j = 0; j < 8; ++j)
                akv[kc][j] = f2bf(kp[(size_t)(kc * 32 + lg * 8 + j) * HW]);
    }

    // ---------- q1: [64 out][128 in], SiLU ----------
    stageW(wb, Wq1, 64, 128, 256, 15, tid);
    __syncthreads();
    {
        f32x4 acc[4] = {};
        #pragma unroll
        for (int t = 0; t < 4; ++t)
            #pragma unroll
            for (int kc = 0; kc < 4; ++kc)
                MFMA16(acc[t], aq[kc], ldB(wb, 256, 15, t, kc, lane));
        #pragma unroll
        for (int t = 0; t < 4; ++t) {
            float bb = bq1[t * 16 + l15];
            #pragma unroll
            for (int j = 0; j < 4; ++j) {
                float v = acc[t][j] + bb;
                v = v / (1.f + __expf(-v));                    // SiLU
                stD(lds + L_XQ1, 128, 7, wid * 16 + lg * 4 + j, t * 16 + l15, v);
            }
        }
    }
    __syncthreads();

    // ---------- q2: [128 out][64 in] ----------
    stageW(wb, Wq2, 128, 64, 128, 7, tid);
    __syncthreads();
    f32x4 qy[8] = {};
    {
        u16x8 a0 = ldA(lds + L_XQ1, 128, 7, rA, 0, lane);
        u16x8 a1 = ldA(lds + L_XQ1, 128, 7, rA, 1, lane);
        #pragma unroll
        for (int t = 0; t < 8; ++t) {
            MFMA16(qy[t], a0, ldB(wb, 128, 7, t, 0, lane));
            MFMA16(qy[t], a1, ldB(wb, 128, 7, t, 1, lane));
            float bb = bq2[t * 16 + l15];
            #pragma unroll
            for (int j = 0; j < 4; ++j) qy[t][j] += bb;
        }
    }
    __syncthreads();

    // ---------- key: [128][256] in two 32KB halves; att = query * key ----------
    f32x4 ka[8] = {};
    stageW(wb, Wk, 64, 256, 512, 31, tid);
    __syncthreads();
    #pragma unroll
    for (int t = 0; t < 4; ++t)
        #pragma unroll
        for (int kc = 0; kc < 8; ++kc)
            MFMA16(ka[t], akv[kc], ldB(wb, 512, 31, t, kc, lane));
    __syncthreads();
    stageW(wb, Wk + 64 * 256, 64, 256, 512, 31, tid);
    __syncthreads();
    #pragma unroll
    for (int t = 0; t < 4; ++t)
        #pragma unroll
        for (int kc = 0; kc < 8; ++kc)
            MFMA16(ka[4 + t], akv[kc], ldB(wb, 512, 31, t, kc, lane));
    #pragma unroll
    for (int t = 0; t < 8; ++t) {
        float bb = bk[t * 16 + l15];
        #pragma unroll
        for (int j = 0; j < 4; ++j) ka[t][j] = (ka[t][j] + bb) * qy[t][j];
    }

    // ---------- L2-normalize over 128 ch + softmax (all in-register, 16-lane trees) ----------
    {
        float ss[4] = {0.f, 0.f, 0.f, 0.f};
        #pragma unroll
        for (int t = 0; t < 8; ++t)
            #pragma unroll
            for (int j = 0; j < 4; ++j) ss[j] += ka[t][j] * ka[t][j];
        float mx[4];
        #pragma unroll
        for (int j = 0; j < 4; ++j) {
            ss[j] = 1.f / fmaxf(sqrtf(red16_sum(ss[j])), 1e-8f);
            mx[j] = -1e30f;
        }
        #pragma unroll
        for (int t = 0; t < 8; ++t)
            #pragma unroll
            for (int j = 0; j < 4; ++j) {
                ka[t][j] *= ss[j];
                mx[j] = fmaxf(mx[j], ka[t][j]);
            }
        #pragma unroll
        for (int j = 0; j < 4; ++j) mx[j] = red16_max(mx[j]);
        float sm[4] = {0.f, 0.f, 0.f, 0.f};
        #pragma unroll
        for (int t = 0; t < 8; ++t)
            #pragma unroll
            for (int j = 0; j < 4; ++j) {
                ka[t][j] = __expf(ka[t][j] - mx[j]);
                sm[j] += ka[t][j];
            }
        #pragma unroll
        for (int j = 0; j < 4; ++j) sm[j] = 1.f / red16_sum(sm[j]);
        #pragma unroll
        for (int t = 0; t < 8; ++t)
            #pragma unroll
            for (int j = 0; j < 4; ++j) ka[t][j] *= sm[j];
    }
    __syncthreads();

    // ---------- value (two halves); x = p * value -> Xmid ----------
    stageW(wb, Wv, 64, 256, 512, 31, tid);
    __syncthreads();
    {
        f32x4 va[8] = {};
        #pragma unroll
        for (int t = 0; t < 4; ++t)
            #pragma unroll
            for (int kc = 0; kc < 8; ++kc)
                MFMA16(va[t], akv[kc], ldB(wb, 512, 31, t, kc, lane));
        __syncthreads();
        stageW(wb, Wv + 64 * 256, 64, 256, 512, 31, tid);
        __syncthreads();
        #pragma unroll
        for (int t = 0; t < 4; ++t)
            #pragma unroll
            for (int kc = 0; kc < 8; ++kc)
                MFMA16(va[4 + t], akv[kc], ldB(wb, 512, 31, t, kc, lane));
        #pragma unroll
        for (int t = 0; t < 8; ++t) {
            float bb = bv[t * 16 + l15];
            #pragma unroll
            for (int j = 0; j < 4; ++j) {
                float x = ka[t][j] * (va[t][j] + bb);
                stD(lds + L_XMID, 256, 15, wid * 16 + lg * 4 + j, t * 16 + l15, x);
            }
        }
    }
    __syncthreads();

    // ---------- res: [32][384] over concat(kv,q), LN32 + relu (kept in regs) ----------
    f32x4 ra[2] = {};
    stageW(wb, Wre, 32, 384, 1024, 31, tid);
    __syncthreads();
    #pragma unroll
    for (int t = 0; t < 2; ++t) {
        #pragma unroll
        for (int kc = 0; kc < 8; ++kc)
            MFMA16(ra[t], akv[kc], ldB(wb, 1024, 31, t, kc, lane));
        #pragma unroll
        for (int kc = 8; kc < 12; ++kc)
            MFMA16(ra[t], aq[kc - 8], ldB(wb, 1024, 31, t, kc, lane));
    }
    {
        float mu[4], vr[4];
        #pragma unroll
        for (int j = 0; j < 4; ++j)
            mu[j] = red16_sum(ra[0][j] + ra[1][j]) * (1.f / 32.f);
        #pragma unroll
        for (int j = 0; j < 4; ++j) {
            float d0 = ra[0][j] - mu[j], d1 = ra[1][j] - mu[j];
            vr[j] = rsqrtf(red16_sum(d0 * d0 + d1 * d1) * (1.f / 32.f) + 1e-5f);
        }
        #pragma unroll
        for (int t = 0; t < 2; ++t) {
            float g = gre[t * 16 + l15], be = bere[t * 16 + l15];
            #pragma unroll
            for (int j = 0; j < 4; ++j)
                ra[t][j] = fmaxf((ra[t][j] - mu[j]) * vr[j] * g + be, 0.f);
        }
    }
    __syncthreads();

    // ---------- att conv [128][128] + LN128 + relu -> Xcat[:,0:128]; res -> Xcat[:,128:160] ----------
    stageW(wb, Wat, 128, 128, 256, 15, tid);
    __syncthreads();
    {
        u16x8 am[4];
        #pragma unroll
        for (int kc = 0; kc < 4; ++kc)
            am[kc] = ldA(lds + L_XMID, 256, 15, rA, kc, lane);
        f32x4 xa[8] = {};
        #pragma unroll
        for (int t = 0; t < 8; ++t)
            #pragma unroll
            for (int kc = 0; kc < 4; ++kc)
                MFMA16(xa[t], am[kc], ldB(wb, 256, 15, t, kc, lane));
        #pragma unroll
        for (int t = 0; t < 8; ++t) {
            float bb = bat[t * 16 + l15];
            #pragma unroll
            for (int j = 0; j < 4; ++j) xa[t][j] += bb;
        }
        float mu[4], vr[4];
        #pragma unroll
        for (int j = 0; j < 4; ++j) {
            float s = 0.f;
            #pragma unroll
            for (int t = 0; t < 8; ++t) s += xa[t][j];
            mu[j] = red16_sum(s) * (1.f / 128.f);
        }
        #pragma unroll
        for (int j = 0; j < 4; ++j) {
            float s = 0.f;
            #pragma unroll
            for (int t = 0; t < 8; ++t) { float d = xa[t][j] - mu[j]; s += d * d; }
            vr[j] = rsqrtf(red16_sum(s) * (1.f / 128.f) + 1e-5f);
        }
        #pragma unroll
        for (int t = 0; t < 8; ++t) {
            float g = gat[t * 16 + l15], be = beat[t * 16 + l15];
            #pragma unroll
            for (int j = 0; j < 4; ++j) {
                float v = fmaxf((xa[t][j] - mu[j]) * vr[j] * g + be, 0.f);
                stD(lds + L_XCAT, 512, 31, wid * 16 + lg * 4 + j, t * 16 + l15, v);
            }
        }
        #pragma unroll
        for (int t = 0; t < 2; ++t)
            #pragma unroll
            for (int j = 0; j < 4; ++j)
                stD(lds + L_XCAT, 512, 31, wid * 16 + lg * 4 + j, 128 + t * 16 + l15, ra[t][j]);
    }
    __syncthreads();

    // ---------- d1 [32][160] + LN32 + relu -> Xd2 ----------
    stageW(wb, Wd1, 32, 160, 512, 31, tid);
    __syncthreads();
    {
        u16x8 ac[5];
        #pragma unroll
        for (int kc = 0; kc < 5; ++kc)
            ac[kc] = ldA(lds + L_XCAT, 512, 31, rA, kc, lane);
        f32x4 d1a[2] = {};
        #pragma unroll
        for (int t = 0; t < 2; ++t)
            #pragma unroll
            for (int kc = 0; kc < 5; ++kc)
                MFMA16(d1a[t], ac[kc], ldB(wb, 512, 31, t, kc, lane));
        float mu[4], vr[4];
        #pragma unroll
        for (int j = 0; j < 4; ++j)
            mu[j] = red16_sum(d1a[0][j] + d1a[1][j]) * (1.f / 32.f);
        #pragma unroll
        for (int j = 0; j < 4; ++j) {
            float d0 = d1a[0][j] - mu[j], d1 = d1a[1][j] - mu[j];
            vr[j] = rsqrtf(red16_sum(d0 * d0 + d1 * d1) * (1.f / 32.f) + 1e-5f);
        }
        #pragma unroll
        for (int t = 0; t < 2; ++t) {
            float g = gd1[t * 16 + l15], be = bed1[t * 16 + l15];
            #pragma unroll
            for (int j = 0; j < 4; ++j) {
                float v = fmaxf((d1a[t][j] - mu[j]) * vr[j] * g + be, 0.f);
                stD(lds + L_XD2, 128, 7, wid * 16 + lg * 4 + j, t * 16 + l15, v);
            }
        }
    }
    __syncthreads();

    // ---------- stage Wd2 [16][32] and zero-padded Wd3 [16][16->32] ----------
    stageW(wb, Wd2, 16, 32, 128, 7, tid);
    {
        int n = tid >> 4, kp = tid & 15;
        unsigned val = 0u;
        if (kp < 8) {
            float a = Wd3[n * 16 + 2 * kp], c = Wd3[n * 16 + 2 * kp + 1];
            val = (unsigned)f2bf(a) | ((unsigned)f2bf(c) << 16);
        }
        *(unsigned*)(wb + 4096 + n * 128 + ((4 * kp) ^ ((n & 7) << 4))) = val;
    }
    __syncthreads();

    // ---------- d2 [16][32] + LN16 + relu -> Xd3 (zero-padded K) ----------
    {
        u16x8 a = ldA(lds + L_XD2, 128, 7, rA, 0, lane);
        f32x4 d2a = {};
        MFMA16(d2a, a, ldB(wb, 128, 7, 0, 0, lane));
        float mu[4], vr[4];
        #pragma unroll
        for (int j = 0; j < 4; ++j) mu[j] = red16_sum(d2a[j]) * (1.f / 16.f);
        #pragma unroll
        for (int j = 0; j < 4; ++j) {
            float d = d2a[j] - mu[j];
            vr[j] = rsqrtf(red16_sum(d * d) * (1.f / 16.f) + 1e-5f);
        }
        float g = gd2[l15], be = bed2[l15];
        #pragma unroll
        for (int j = 0; j < 4; ++j) {
            float v = fmaxf((d2a[j] - mu[j]) * vr[j] * g + be, 0.f);
            int rD = wid * 16 + lg * 4 + j;
            stD(lds + L_XD3, 128, 7, rD, l15, v);
            stD(lds + L_XD3, 128, 7, rD, 16 + l15, 0.f);
        }
    }
    __syncthreads();

    // ---------- d3 [16][16] + bias -> out ----------
    {
        u16x8 a = ldA(lds + L_XD3, 128, 7, rA, 0, lane);
        f32x4 oa = {};
        MFMA16(oa, a, ldB(wb + 4096, 128, 7, 0, 0, lane));
        float bb = bd3[l15];
        float* op = out + ((size_t)b * 16 + l15) * HW + (p0 + wid * 16 + lg * 4);
        f32x4 r = oa + bb;
        *(f32x4*)op = r;    // 16B store; 4 lanes of same out-channel form a contiguous 64B run
    }
}

extern "C" void kernel_launch(void* const* d_in, const int* in_sizes, int n_in,
                              void* d_out, int out_size, void* d_ws, size_t ws_size,
                              hipStream_t stream) {
    (void)in_sizes; (void)n_in; (void)out_size; (void)d_ws; (void)ws_size;
    fused_attres<<<NBLK, 256, 0, stream>>>(
        (const float*)d_in[0],  (const float*)d_in[1],
        (const float*)d_in[2],  (const float*)d_in[3],
        (const float*)d_in[4],  (const float*)d_in[5],
        (const float*)d_in[6],  (const float*)d_in[7],
        (const float*)d_in[8],  (const float*)d_in[9],
        /* d_in[10] = scale, unused by reference */
        (const float*)d_in[11], (const float*)d_in[12],
        (const float*)d_in[13], (const float*)d_in[14],
        (const float*)d_in[15], (const float*)d_in[16], (const float*)d_in[17],
        (const float*)d_in[18], (const float*)d_in[19], (const float*)d_in[20],
        (const float*)d_in[21], (const float*)d_in[22], (const float*)d_in[23],
        (const float*)d_in[24], (const float*)d_in[25],
        (float*)d_out);
}

// Round 3
// 165.105 us; speedup vs baseline: 1.8401x; 1.8401x over previous
//
#include <hip/hip_runtime.h>
#include <hip/hip_bf16.h>

#define HW 50176          // 224*224
#define NBLK 3136         // 4*HW / 64 pixels per block

typedef unsigned short u16x8 __attribute__((ext_vector_type(8)));
typedef __bf16 bf16x8 __attribute__((ext_vector_type(8)));
typedef float f32x4 __attribute__((ext_vector_type(4)));

// ws weight-image offsets (bf16, pre-swizzled exact LDS byte layout)
#define OFF_Q1 0              // [64][256B]  16384
#define OFF_Q2 16384          // [128][128B] 16384
#define OFF_K  32768          // [128][512B] 65536 (two 32KB halves)
#define OFF_V  98304          // [128][512B] 65536
#define OFF_AT 163840         // [128][256B] 32768
#define OFF_RE 196608         // [32][1024B] 32768
#define OFF_D1 229376         // [32][512B]  16384
#define OFF_D2 245760         // [16][128B]  2048
#define OFF_D3 247808         // [16][128B]  2048 (K padded 16->32 with zeros)
#define WS_NEED 249856

// LDS map (80 KB total -> 2 WGs/CU)
#define L_WBUF 0              // 32 KB weight staging buffer
#define L_XMID 32768          // 16 KB  x=att*value [64][128] bf16 S=256
#define L_XD2  32768          //  8 KB  d2 input    [64][32]  bf16 S=128 (reuse)
#define L_XD3  40960          //  8 KB  d3 input    [64][32]  bf16 S=128 (reuse)
#define L_XCAT 49152          // 32 KB  concat      [64][160] bf16 S=512
#define L_XQ1  49152          //  8 KB  q1 out      [64][64]  bf16 S=128 (reuse, dead before XCAT)
#define LDS_BYTES 81920

static __device__ __forceinline__ unsigned short f2bf(float x) {
    unsigned u = __builtin_bit_cast(unsigned, x);
    unsigned r = u + 0x7fffu + ((u >> 16) & 1u);   // RNE (explicit: (__bf16) cast rounds differently -> failed R2)
    return (unsigned short)(r >> 16);
}

static __device__ __forceinline__ float red16_sum(float v) {
    v += __shfl_xor(v, 1); v += __shfl_xor(v, 2);
    v += __shfl_xor(v, 4); v += __shfl_xor(v, 8);
    return v;
}
static __device__ __forceinline__ float red16_max(float v) {
    v = fmaxf(v, __shfl_xor(v, 1)); v = fmaxf(v, __shfl_xor(v, 2));
    v = fmaxf(v, __shfl_xor(v, 4)); v = fmaxf(v, __shfl_xor(v, 8));
    return v;
}

#define MFMA16(acc, a, bfr) (acc) = __builtin_amdgcn_mfma_f32_16x16x32_bf16( \
        __builtin_bit_cast(bf16x8, (a)), __builtin_bit_cast(bf16x8, (bfr)), (acc), 0, 0, 0)

// ---- weight prep: f32 row-major -> bf16 swizzled LDS image in d_ws (once per launch) ----
static __device__ __forceinline__ void prepW(char* dst, const float* __restrict__ W,
                                             int NS, int K, int S, int mask, int gt, int gs) {
    const int kh = K >> 1;
    const int pairs = NS * kh;
    for (int q = gt; q < pairs; q += gs) {
        int n = q / kh;
        int kp = q - n * kh;
        unsigned val = (unsigned)f2bf(W[n * K + 2 * kp]) |
                       ((unsigned)f2bf(W[n * K + 2 * kp + 1]) << 16);
        *(unsigned*)(dst + n * S + ((4 * kp) ^ ((n & mask) << 4))) = val;
    }
}

__global__ void prep_weights(const float* __restrict__ Wq1, const float* __restrict__ Wq2,
                             const float* __restrict__ Wk,  const float* __restrict__ Wv,
                             const float* __restrict__ Wat, const float* __restrict__ Wre,
                             const float* __restrict__ Wd1, const float* __restrict__ Wd2,
                             const float* __restrict__ Wd3, char* __restrict__ ws) {
    int gt = blockIdx.x * 256 + threadIdx.x;
    int gs = gridDim.x * 256;
    prepW(ws + OFF_Q1, Wq1, 64, 128, 256, 15, gt, gs);
    prepW(ws + OFF_Q2, Wq2, 128, 64, 128, 7, gt, gs);
    prepW(ws + OFF_K,  Wk, 128, 256, 512, 31, gt, gs);
    prepW(ws + OFF_V,  Wv, 128, 256, 512, 31, gt, gs);
    prepW(ws + OFF_AT, Wat, 128, 128, 256, 15, gt, gs);
    prepW(ws + OFF_RE, Wre, 32, 384, 1024, 31, gt, gs);
    prepW(ws + OFF_D1, Wd1, 32, 160, 512, 31, gt, gs);
    prepW(ws + OFF_D2, Wd2, 16, 32, 128, 7, gt, gs);
    // D3 zero-padded K 16->32
    for (int q = gt; q < 256; q += gs) {
        int n = q >> 4, kp = q & 15;
        unsigned val = 0u;
        if (kp < 8)
            val = (unsigned)f2bf(Wd3[n * 16 + 2 * kp]) |
                  ((unsigned)f2bf(Wd3[n * 16 + 2 * kp + 1]) << 16);
        *(unsigned*)(ws + OFF_D3 + n * 128 + ((4 * kp) ^ ((n & 7) << 4))) = val;
    }
}

// ---- zero-VALU LDS staging: linear copy of a pre-swizzled image via global_load_lds ----
template <int BYTES>
static __device__ __forceinline__ void stageLDS(char* lds_dst, const char* __restrict__ src,
                                                int wid, int lane) {
    constexpr int per = BYTES >> 2;                 // bytes per wave
    const char* s = src + wid * per + lane * 16;
    char* d = lds_dst + wid * per;
    #pragma unroll
    for (int i = 0; i < per; i += 1024)
        __builtin_amdgcn_global_load_lds(
            (const __attribute__((address_space(1))) unsigned*)(s + i),
            (__attribute__((address_space(3))) unsigned*)(d + i), 16, 0, 0);
}

static __device__ __forceinline__ u16x8 ldB(const char* lds, int S, int mask,
                                            int t, int kc, int lane) {
    int n = t * 16 + (lane & 15);
    int kb = kc * 64 + ((lane >> 4) << 4);
    return *(const u16x8*)(lds + n * S + (kb ^ ((n & mask) << 4)));
}
static __device__ __forceinline__ u16x8 ldA(const char* lds, int S, int mask,
                                            int rA, int kc, int lane) {
    int kb = kc * 64 + ((lane >> 4) << 4);
    return *(const u16x8*)(lds + rA * S + (kb ^ ((rA & mask) << 4)));
}
static __device__ __forceinline__ void stD(char* lds, int S, int mask,
                                           int rD, int c, float v) {
    *(unsigned short*)(lds + rD * S + ((2 * c) ^ ((rD & mask) << 4))) = f2bf(v);
}

__global__ __launch_bounds__(256, 2) void fused_attres(
        const float* __restrict__ kvin, const float* __restrict__ qin,
        const char* __restrict__ ws,
        const float* __restrict__ bk,  const float* __restrict__ bv,
        const float* __restrict__ bq1, const float* __restrict__ bq2,
        const float* __restrict__ bat, const float* __restrict__ gat, const float* __restrict__ beat,
        const float* __restrict__ gre, const float* __restrict__ bere,
        const float* __restrict__ gd1, const float* __restrict__ bed1,
        const float* __restrict__ gd2, const float* __restrict__ bed2,
        const float* __restrict__ bd3,
        float* __restrict__ out)
{
    __shared__ __align__(16) char lds[LDS_BYTES];
    const int tid  = threadIdx.x;
    const int lane = tid & 63;
    const int wid  = tid >> 6;
    const int l15  = lane & 15;
    const int lg   = lane >> 4;
    const int P0 = blockIdx.x * 64;
    const int b  = P0 / HW;
    const int p0 = P0 - b * HW;
    const int rA = wid * 16 + l15;
    char* wb = lds + L_WBUF;

    // stage q1 weights early (in flight during input loads)
    stageLDS<16384>(wb, ws + OFF_Q1, wid, lane);

    // ---------- A fragments of raw inputs straight from global (f32 -> bf16, explicit RNE) ----------
    u16x8 aq[4], akv[8];
    {
        const float* qp = qin + (size_t)b * 128 * HW + (p0 + rA);
        #pragma unroll
        for (int kc = 0; kc < 4; ++kc)
            #pragma unroll
            for (int j = 0; j < 8; ++j)
                aq[kc][j] = f2bf(qp[(size_t)(kc * 32 + lg * 8 + j) * HW]);
        const float* kp = kvin + (size_t)b * 256 * HW + (p0 + rA);
        #pragma unroll
        for (int kc = 0; kc < 8; ++kc)
            #pragma unroll
            for (int j = 0; j < 8; ++j)
                akv[kc][j] = f2bf(kp[(size_t)(kc * 32 + lg * 8 + j) * HW]);
    }
    __syncthreads();

    // ---------- q1: [64 out][128 in], SiLU ----------
    {
        f32x4 acc[4] = {};
        #pragma unroll
        for (int t = 0; t < 4; ++t)
            #pragma unroll
            for (int kc = 0; kc < 4; ++kc)
                MFMA16(acc[t], aq[kc], ldB(wb, 256, 15, t, kc, lane));
        #pragma unroll
        for (int t = 0; t < 4; ++t) {
            float bb = bq1[t * 16 + l15];
            #pragma unroll
            for (int j = 0; j < 4; ++j) {
                float v = acc[t][j] + bb;
                v = v / (1.f + __expf(-v));                    // SiLU
                stD(lds + L_XQ1, 128, 7, wid * 16 + lg * 4 + j, t * 16 + l15, v);
            }
        }
    }
    __syncthreads();

    // ---------- q2: [128 out][64 in] ----------
    stageLDS<16384>(wb, ws + OFF_Q2, wid, lane);
    __syncthreads();
    f32x4 qy[8] = {};
    {
        u16x8 a0 = ldA(lds + L_XQ1, 128, 7, rA, 0, lane);
        u16x8 a1 = ldA(lds + L_XQ1, 128, 7, rA, 1, lane);
        #pragma unroll
        for (int t = 0; t < 8; ++t) {
            MFMA16(qy[t], a0, ldB(wb, 128, 7, t, 0, lane));
            MFMA16(qy[t], a1, ldB(wb, 128, 7, t, 1, lane));
            float bb = bq2[t * 16 + l15];
            #pragma unroll
            for (int j = 0; j < 4; ++j) qy[t][j] += bb;
        }
    }
    __syncthreads();

    // ---------- key: [128][256] in two 32KB halves; att = query * key ----------
    f32x4 ka[8] = {};
    stageLDS<32768>(wb, ws + OFF_K, wid, lane);
    __syncthreads();
    #pragma unroll
    for (int t = 0; t < 4; ++t)
        #pragma unroll
        for (int kc = 0; kc < 8; ++kc)
            MFMA16(ka[t], akv[kc], ldB(wb, 512, 31, t, kc, lane));
    __syncthreads();
    stageLDS<32768>(wb, ws + OFF_K + 32768, wid, lane);
    __syncthreads();
    #pragma unroll
    for (int t = 0; t < 4; ++t)
        #pragma unroll
        for (int kc = 0; kc < 8; ++kc)
            MFMA16(ka[4 + t], akv[kc], ldB(wb, 512, 31, t, kc, lane));
    #pragma unroll
    for (int t = 0; t < 8; ++t) {
        float bb = bk[t * 16 + l15];
        #pragma unroll
        for (int j = 0; j < 4; ++j) ka[t][j] = (ka[t][j] + bb) * qy[t][j];
    }

    // ---------- L2-normalize over 128 ch + softmax (in-register, 16-lane trees) ----------
    {
        float ss[4] = {0.f, 0.f, 0.f, 0.f};
        #pragma unroll
        for (int t = 0; t < 8; ++t)
            #pragma unroll
            for (int j = 0; j < 4; ++j) ss[j] += ka[t][j] * ka[t][j];
        float mx[4];
        #pragma unroll
        for (int j = 0; j < 4; ++j) {
            ss[j] = 1.f / fmaxf(sqrtf(red16_sum(ss[j])), 1e-8f);
            mx[j] = -1e30f;
        }
        #pragma unroll
        for (int t = 0; t < 8; ++t)
            #pragma unroll
            for (int j = 0; j < 4; ++j) {
                ka[t][j] *= ss[j];
                mx[j] = fmaxf(mx[j], ka[t][j]);
            }
        #pragma unroll
        for (int j = 0; j < 4; ++j) mx[j] = red16_max(mx[j]);
        float sm[4] = {0.f, 0.f, 0.f, 0.f};
        #pragma unroll
        for (int t = 0; t < 8; ++t)
            #pragma unroll
            for (int j = 0; j < 4; ++j) {
                ka[t][j] = __expf(ka[t][j] - mx[j]);
                sm[j] += ka[t][j];
            }
        #pragma unroll
        for (int j = 0; j < 4; ++j) sm[j] = 1.f / red16_sum(sm[j]);
        #pragma unroll
        for (int t = 0; t < 8; ++t)
            #pragma unroll
            for (int j = 0; j < 4; ++j) ka[t][j] *= sm[j];
    }
    __syncthreads();

    // ---------- value (two halves); x = p * value -> Xmid ----------
    stageLDS<32768>(wb, ws + OFF_V, wid, lane);
    __syncthreads();
    {
        f32x4 va[8] = {};
        #pragma unroll
        for (int t = 0; t < 4; ++t)
            #pragma unroll
            for (int kc = 0; kc < 8; ++kc)
                MFMA16(va[t], akv[kc], ldB(wb, 512, 31, t, kc, lane));
        __syncthreads();
        stageLDS<32768>(wb, ws + OFF_V + 32768, wid, lane);
        __syncthreads();
        #pragma unroll
        for (int t = 0; t < 4; ++t)
            #pragma unroll
            for (int kc = 0; kc < 8; ++kc)
                MFMA16(va[4 + t], akv[kc], ldB(wb, 512, 31, t, kc, lane));
        #pragma unroll
        for (int t = 0; t < 8; ++t) {
            float bb = bv[t * 16 + l15];
            #pragma unroll
            for (int j = 0; j < 4; ++j) {
                float x = ka[t][j] * (va[t][j] + bb);
                stD(lds + L_XMID, 256, 15, wid * 16 + lg * 4 + j, t * 16 + l15, x);
            }
        }
    }
    __syncthreads();

    // ---------- res: [32][384] over concat(kv,q), LN32 + relu (kept in regs) ----------
    f32x4 ra[2] = {};
    stageLDS<32768>(wb, ws + OFF_RE, wid, lane);
    __syncthreads();
    #pragma unroll
    for (int t = 0; t < 2; ++t) {
        #pragma unroll
        for (int kc = 0; kc < 8; ++kc)
            MFMA16(ra[t], akv[kc], ldB(wb, 1024, 31, t, kc, lane));
        #pragma unroll
        for (int kc = 8; kc < 12; ++kc)
            MFMA16(ra[t], aq[kc - 8], ldB(wb, 1024, 31, t, kc, lane));
    }
    {
        float mu[4], vr[4];
        #pragma unroll
        for (int j = 0; j < 4; ++j)
            mu[j] = red16_sum(ra[0][j] + ra[1][j]) * (1.f / 32.f);
        #pragma unroll
        for (int j = 0; j < 4; ++j) {
            float d0 = ra[0][j] - mu[j], d1 = ra[1][j] - mu[j];
            vr[j] = rsqrtf(red16_sum(d0 * d0 + d1 * d1) * (1.f / 32.f) + 1e-5f);
        }
        #pragma unroll
        for (int t = 0; t < 2; ++t) {
            float g = gre[t * 16 + l15], be = bere[t * 16 + l15];
            #pragma unroll
            for (int j = 0; j < 4; ++j)
                ra[t][j] = fmaxf((ra[t][j] - mu[j]) * vr[j] * g + be, 0.f);
        }
    }
    __syncthreads();

    // ---------- att conv [128][128] + LN128 + relu -> Xcat[:,0:128]; res -> Xcat[:,128:160] ----------
    stageLDS<32768>(wb, ws + OFF_AT, wid, lane);
    __syncthreads();
    {
        u16x8 am[4];
        #pragma unroll
        for (int kc = 0; kc < 4; ++kc)
            am[kc] = ldA(lds + L_XMID, 256, 15, rA, kc, lane);
        f32x4 xa[8] = {};
        #pragma unroll
        for (int t = 0; t < 8; ++t)
            #pragma unroll
            for (int kc = 0; kc < 4; ++kc)
                MFMA16(xa[t], am[kc], ldB(wb, 256, 15, t, kc, lane));
        #pragma unroll
        for (int t = 0; t < 8; ++t) {
            float bb = bat[t * 16 + l15];
            #pragma unroll
            for (int j = 0; j < 4; ++j) xa[t][j] += bb;
        }
        float mu[4], vr[4];
        #pragma unroll
        for (int j = 0; j < 4; ++j) {
            float s = 0.f;
            #pragma unroll
            for (int t = 0; t < 8; ++t) s += xa[t][j];
            mu[j] = red16_sum(s) * (1.f / 128.f);
        }
        #pragma unroll
        for (int j = 0; j < 4; ++j) {
            float s = 0.f;
            #pragma unroll
            for (int t = 0; t < 8; ++t) { float d = xa[t][j] - mu[j]; s += d * d; }
            vr[j] = rsqrtf(red16_sum(s) * (1.f / 128.f) + 1e-5f);
        }
        #pragma unroll
        for (int t = 0; t < 8; ++t) {
            float g = gat[t * 16 + l15], be = beat[t * 16 + l15];
            #pragma unroll
            for (int j = 0; j < 4; ++j) {
                float v = fmaxf((xa[t][j] - mu[j]) * vr[j] * g + be, 0.f);
                stD(lds + L_XCAT, 512, 31, wid * 16 + lg * 4 + j, t * 16 + l15, v);
            }
        }
        #pragma unroll
        for (int t = 0; t < 2; ++t)
            #pragma unroll
            for (int j = 0; j < 4; ++j)
                stD(lds + L_XCAT, 512, 31, wid * 16 + lg * 4 + j, 128 + t * 16 + l15, ra[t][j]);
    }
    __syncthreads();

    // ---------- d1 [32][160] + LN32 + relu -> Xd2 ----------
    stageLDS<16384>(wb, ws + OFF_D1, wid, lane);
    __syncthreads();
    {
        u16x8 ac[5];
        #pragma unroll
        for (int kc = 0; kc < 5; ++kc)
            ac[kc] = ldA(lds + L_XCAT, 512, 31, rA, kc, lane);
        f32x4 d1a[2] = {};
        #pragma unroll
        for (int t = 0; t < 2; ++t)
            #pragma unroll
            for (int kc = 0; kc < 5; ++kc)
                MFMA16(d1a[t], ac[kc], ldB(wb, 512, 31, t, kc, lane));
        float mu[4], vr[4];
        #pragma unroll
        for (int j = 0; j < 4; ++j)
            mu[j] = red16_sum(d1a[0][j] + d1a[1][j]) * (1.f / 32.f);
        #pragma unroll
        for (int j = 0; j < 4; ++j) {
            float d0 = d1a[0][j] - mu[j], d1 = d1a[1][j] - mu[j];
            vr[j] = rsqrtf(red16_sum(d0 * d0 + d1 * d1) * (1.f / 32.f) + 1e-5f);
        }
        #pragma unroll
        for (int t = 0; t < 2; ++t) {
            float g = gd1[t * 16 + l15], be = bed1[t * 16 + l15];
            #pragma unroll
            for (int j = 0; j < 4; ++j) {
                float v = fmaxf((d1a[t][j] - mu[j]) * vr[j] * g + be, 0.f);
                stD(lds + L_XD2, 128, 7, wid * 16 + lg * 4 + j, t * 16 + l15, v);
            }
        }
    }
    __syncthreads();

    // ---------- stage Wd2 [16][32] + padded Wd3 (contiguous 4KB image) ----------
    stageLDS<4096>(wb, ws + OFF_D2, wid, lane);
    __syncthreads();

    // ---------- d2 [16][32] + LN16 + relu -> Xd3 (zero-padded K) ----------
    {
        u16x8 a = ldA(lds + L_XD2, 128, 7, rA, 0, lane);
        f32x4 d2a = {};
        MFMA16(d2a, a, ldB(wb, 128, 7, 0, 0, lane));
        float mu[4], vr[4];
        #pragma unroll
        for (int j = 0; j < 4; ++j) mu[j] = red16_sum(d2a[j]) * (1.f / 16.f);
        #pragma unroll
        for (int j = 0; j < 4; ++j) {
            float d = d2a[j] - mu[j];
            vr[j] = rsqrtf(red16_sum(d * d) * (1.f / 16.f) + 1e-5f);
        }
        float g = gd2[l15], be = bed2[l15];
        #pragma unroll
        for (int j = 0; j < 4; ++j) {
            float v = fmaxf((d2a[j] - mu[j]) * vr[j] * g + be, 0.f);
            int rD = wid * 16 + lg * 4 + j;
            stD(lds + L_XD3, 128, 7, rD, l15, v);
            stD(lds + L_XD3, 128, 7, rD, 16 + l15, 0.f);
        }
    }
    __syncthreads();

    // ---------- d3 [16][16] + bias -> out ----------
    {
        u16x8 a = ldA(lds + L_XD3, 128, 7, rA, 0, lane);
        f32x4 oa = {};
        MFMA16(oa, a, ldB(wb + 2048, 128, 7, 0, 0, lane));
        float bb = bd3[l15];
        float* op = out + ((size_t)b * 16 + l15) * HW + (p0 + wid * 16 + lg * 4);
        f32x4 r = oa + bb;
        *(f32x4*)op = r;
    }
}

extern "C" void kernel_launch(void* const* d_in, const int* in_sizes, int n_in,
                              void* d_out, int out_size, void* d_ws, size_t ws_size,
                              hipStream_t stream) {
    (void)in_sizes; (void)n_in; (void)out_size; (void)ws_size;
    prep_weights<<<128, 256, 0, stream>>>(
        (const float*)d_in[6],  (const float*)d_in[8],
        (const float*)d_in[2],  (const float*)d_in[4],
        (const float*)d_in[11], (const float*)d_in[15],
        (const float*)d_in[18], (const float*)d_in[21],
        (const float*)d_in[24], (char*)d_ws);
    fused_attres<<<NBLK, 256, 0, stream>>>(
        (const float*)d_in[0],  (const float*)d_in[1],
        (const char*)d_ws,
        (const float*)d_in[3],  (const float*)d_in[5],
        (const float*)d_in[7],  (const float*)d_in[9],
        (const float*)d_in[12], (const float*)d_in[13], (const float*)d_in[14],
        (const float*)d_in[16], (const float*)d_in[17],
        (const float*)d_in[19], (const float*)d_in[20],
        (const float*)d_in[22], (const float*)d_in[23],
        (const float*)d_in[25],
        (float*)d_out);
}